// Round 1
// baseline (1172.402 us; speedup 1.0000x reference)
//
#include <hip/hip_runtime.h>
#include <math.h>
#include <limits.h>

#define N_NODES 50000
#define N_EDGES 800000
#define N_GRAPHS 64
#define IN_CH 128
#define EMB 64
#define POOL_CHUNK 256

// ---------- degree / norm precompute (shared by all 4 layers) ----------
__global__ void init_deg_k(float* deg) {
    int i = blockIdx.x * blockDim.x + threadIdx.x;
    if (i < N_NODES) deg[i] = 1.0f;  // self-loop weight
}

__global__ void accum_deg_k(const int* __restrict__ dst, const float* __restrict__ w,
                            float* deg) {
    int e = blockIdx.x * blockDim.x + threadIdx.x;
    if (e < N_EDGES) atomicAdd(&deg[dst[e]], w[e]);
}

__global__ void dinv_k(float* deg) {
    int i = blockIdx.x * blockDim.x + threadIdx.x;
    if (i < N_NODES) {
        float d = deg[i];
        deg[i] = d > 0.f ? rsqrtf(d) : 0.f;  // in-place: deg -> dinv
    }
}

__global__ void norm_k(const int* __restrict__ src, const int* __restrict__ dst,
                       const float* __restrict__ w, const float* __restrict__ dinv,
                       float* __restrict__ norm) {
    int e = blockIdx.x * blockDim.x + threadIdx.x;
    if (e < N_EDGES) norm[e] = dinv[src[e]] * w[e] * dinv[dst[e]];
}

// ---------- h = A @ W  (W staged in LDS; wave = one row, lane = col) ----------
template<int K>
__global__ __launch_bounds__(256) void gemm_k(const float* __restrict__ A,
                                              const float* __restrict__ W,
                                              float* __restrict__ out) {
    __shared__ float Wl[K * EMB];
    for (int i = threadIdx.x; i < K * EMB; i += 256) Wl[i] = W[i];
    __syncthreads();
    int col = threadIdx.x & 63;
    int row = blockIdx.x * 4 + (threadIdx.x >> 6);
    if (row >= N_NODES) return;
    const float* a = A + (long)row * K;
    float acc = 0.f;
#pragma unroll 8
    for (int k = 0; k < K; ++k) acc += a[k] * Wl[k * EMB + col];
    out[row * EMB + col] = acc;
}

// ---------- aggregation ----------
// out[i] = dinv[i]^2 * h[i] + b   (self-loop term + bias)
__global__ void agg_init_k(const float* __restrict__ h, const float* __restrict__ dinv,
                           const float* __restrict__ b, float* __restrict__ out) {
    int i = blockIdx.x * blockDim.x + threadIdx.x;
    if (i >= N_NODES * EMB) return;
    int node = i >> 6, c = i & 63;
    float di = dinv[node];
    out[i] = di * di * h[i] + b[c];
}

// thread = (edge, channel); lane = channel -> coalesced gather + coalesced atomics
__global__ void agg_edges_k(const float* __restrict__ h, const float* __restrict__ norm,
                            const int* __restrict__ src, const int* __restrict__ dst,
                            float* __restrict__ out) {
    unsigned idx = blockIdx.x * blockDim.x + threadIdx.x;
    unsigned e = idx >> 6;
    if (e >= N_EDGES) return;
    int c = idx & 63;
    int s = src[e], d = dst[e];
    atomicAdd(&out[d * EMB + c], norm[e] * h[s * EMB + c]);
}

__global__ void tanh_k(float* h) {
    int i = blockIdx.x * blockDim.x + threadIdx.x;
    if (i < N_NODES * EMB) h[i] = tanhf(h[i]);
}

// ---------- pooling ----------
__device__ inline int f2ord(float x) {
    int b = __float_as_int(x);
    return b >= 0 ? b : (b ^ 0x7fffffff);
}
__device__ inline float ord2f(int k) {
    return __int_as_float(k >= 0 ? k : (k ^ 0x7fffffff));
}

__global__ void pool_init_k(int* gmax, float* gsum, int* cnt) {
    int i = blockIdx.x * blockDim.x + threadIdx.x;
    if (i < N_GRAPHS * EMB) { gmax[i] = INT_MIN; gsum[i] = 0.f; }
    if (i < N_GRAPHS) cnt[i] = 0;
}

// wave walks POOL_CHUNK contiguous nodes (batch sorted); lane = channel.
__global__ void pool_k(const float* __restrict__ h, const int* __restrict__ batch,
                       int* gmax, float* gsum, int* cnt) {
    int wave = (blockIdx.x * blockDim.x + threadIdx.x) >> 6;
    int lane = threadIdx.x & 63;
    int start = wave * POOL_CHUNK;
    if (start >= N_NODES) return;
    int end = min(start + POOL_CHUNK, N_NODES);
    int curg = batch[start];
    float mx = -INFINITY, sm = 0.f;
    int ct = 0;
    for (int i = start; i < end; ++i) {
        int g = batch[i];
        if (g != curg) {
            atomicMax(&gmax[curg * EMB + lane], f2ord(mx));
            atomicAdd(&gsum[curg * EMB + lane], sm);
            if (lane == 0) atomicAdd(&cnt[curg], ct);
            curg = g; mx = -INFINITY; sm = 0.f; ct = 0;
        }
        float v = h[i * EMB + lane];
        mx = fmaxf(mx, v);
        sm += v;
        ++ct;
    }
    atomicMax(&gmax[curg * EMB + lane], f2ord(mx));
    atomicAdd(&gsum[curg * EMB + lane], sm);
    if (lane == 0) atomicAdd(&cnt[curg], ct);
}

// ---------- head: out[g] = [gmax | gmean] @ Wout + bout ----------
__global__ void final_k(const int* __restrict__ gmax, const float* __restrict__ gsum,
                        const int* __restrict__ cnt, const float* __restrict__ Wout,
                        const float* __restrict__ bout, float* __restrict__ out) {
    int g = threadIdx.x;
    if (g >= N_GRAPHS) return;
    float c = fmaxf((float)cnt[g], 1.0f);
    float acc = bout[0];
    for (int ch = 0; ch < EMB; ++ch) {
        acc += ord2f(gmax[g * EMB + ch]) * Wout[ch]
             + (gsum[g * EMB + ch] / c) * Wout[EMB + ch];
    }
    out[g] = acc;
}

extern "C" void kernel_launch(void* const* d_in, const int* in_sizes, int n_in,
                              void* d_out, int out_size, void* d_ws, size_t ws_size,
                              hipStream_t stream) {
    const float* x         = (const float*)d_in[0];
    const int*   edge_idx  = (const int*)d_in[1];
    const float* edge_attr = (const float*)d_in[2];
    const int*   batch     = (const int*)d_in[3];
    const float* W0 = (const float*)d_in[4];
    const float* b0 = (const float*)d_in[5];
    const float* W1 = (const float*)d_in[6];
    const float* b1 = (const float*)d_in[7];
    const float* W2 = (const float*)d_in[8];
    const float* b2 = (const float*)d_in[9];
    const float* W3 = (const float*)d_in[10];
    const float* b3 = (const float*)d_in[11];
    const float* Wout = (const float*)d_in[12];
    const float* bout = (const float*)d_in[13];
    float* out = (float*)d_out;

    const int* src = edge_idx;            // edge_index[0]
    const int* dst = edge_idx + N_EDGES;  // edge_index[1]

    // workspace layout (~29.3 MB)
    char* ws = (char*)d_ws;
    float* deg  = (float*)ws; ws += ((N_NODES + 255) / 256) * 256 * sizeof(float);
    float* norm = (float*)ws; ws += (size_t)N_EDGES * sizeof(float);
    float* bufL = (float*)ws; ws += (size_t)N_NODES * EMB * sizeof(float);
    float* bufH = (float*)ws; ws += (size_t)N_NODES * EMB * sizeof(float);
    int*   gmax = (int*)ws;   ws += N_GRAPHS * EMB * sizeof(int);
    float* gsum = (float*)ws; ws += N_GRAPHS * EMB * sizeof(float);
    int*   cnt  = (int*)ws;   ws += N_GRAPHS * sizeof(int);

    const int nodeB  = (N_NODES + 255) / 256;
    const int edgeB  = (N_EDGES + 255) / 256;
    const int ncB    = (N_NODES * EMB + 255) / 256;
    const int gemmB  = (N_NODES + 3) / 4;
    const int edgeCB = (N_EDGES * EMB) / 256;  // exact: 800000*64 % 256 == 0

    // norm precompute (once for all 4 layers)
    init_deg_k<<<nodeB, 256, 0, stream>>>(deg);
    accum_deg_k<<<edgeB, 256, 0, stream>>>(dst, edge_attr, deg);
    dinv_k<<<nodeB, 256, 0, stream>>>(deg);
    norm_k<<<edgeB, 256, 0, stream>>>(src, dst, edge_attr, deg, norm);

    const float* Wl[4] = {W0, W1, W2, W3};
    const float* bl[4] = {b0, b1, b2, b3};
    for (int l = 0; l < 4; ++l) {
        if (l == 0) gemm_k<IN_CH><<<gemmB, 256, 0, stream>>>(x, Wl[0], bufL);
        else        gemm_k<EMB>  <<<gemmB, 256, 0, stream>>>(bufH, Wl[l], bufL);
        agg_init_k<<<ncB, 256, 0, stream>>>(bufL, deg, bl[l], bufH);
        agg_edges_k<<<edgeCB, 256, 0, stream>>>(bufL, norm, src, dst, bufH);
        tanh_k<<<ncB, 256, 0, stream>>>(bufH);
    }

    pool_init_k<<<(N_GRAPHS * EMB + 255) / 256, 256, 0, stream>>>(gmax, gsum, cnt);
    int poolWaves = (N_NODES + POOL_CHUNK - 1) / POOL_CHUNK;
    pool_k<<<(poolWaves * 64 + 255) / 256, 256, 0, stream>>>(bufH, batch, gmax, gsum, cnt);
    final_k<<<1, 64, 0, stream>>>(gmax, gsum, cnt, Wout, bout, out);
}

// Round 2
// 792.233 us; speedup vs baseline: 1.4799x; 1.4799x over previous
//
#include <hip/hip_runtime.h>
#include <math.h>
#include <limits.h>

#define N_NODES 50000
#define N_EDGES 800000
#define N_GRAPHS 64
#define IN_CH 128
#define EMB 64
#define POOL_CHUNK 256
#define SCAN_T 1024

// ---------- init: deg=1 (self-loop), counts=0 ----------
__global__ void init_k(float* deg, int* counts) {
    int i = blockIdx.x * blockDim.x + threadIdx.x;
    if (i < N_NODES) { deg[i] = 1.0f; counts[i] = 0; }
}

// ---------- fused histogram: in-degree count + weighted degree ----------
__global__ void hist_k(const int* __restrict__ dst, const float* __restrict__ w,
                       float* deg, int* counts) {
    int e = blockIdx.x * blockDim.x + threadIdx.x;
    if (e >= N_EDGES) return;
    int d = dst[e];
    atomicAdd(&counts[d], 1);
    atomicAdd(&deg[d], w[e]);
}

__global__ void dinv_k(float* deg) {
    int i = blockIdx.x * blockDim.x + threadIdx.x;
    if (i < N_NODES) {
        float d = deg[i];
        deg[i] = d > 0.f ? rsqrtf(d) : 0.f;  // in-place: deg -> dinv
    }
}

// ---------- single-block exclusive scan of counts -> row_start, cursor ----------
__global__ __launch_bounds__(SCAN_T) void scan_k(const int* __restrict__ counts,
                                                 int* __restrict__ row_start,
                                                 int* __restrict__ cursor) {
    __shared__ int part[SCAN_T];
    const int CHUNK = (N_NODES + SCAN_T - 1) / SCAN_T;  // 49
    int t = threadIdx.x;
    int beg = t * CHUNK, end = min(beg + CHUNK, N_NODES);
    int s = 0;
    for (int i = beg; i < end; ++i) s += counts[i];
    part[t] = s;
    __syncthreads();
    for (int off = 1; off < SCAN_T; off <<= 1) {
        int v = (t >= off) ? part[t - off] : 0;
        __syncthreads();
        part[t] += v;
        __syncthreads();
    }
    int pre = (t == 0) ? 0 : part[t - 1];
    for (int i = beg; i < end; ++i) {
        row_start[i] = pre;
        cursor[i] = pre;
        pre += counts[i];
    }
    if (t == SCAN_T - 1) row_start[N_NODES] = part[SCAN_T - 1];
}

// ---------- scatter edges into CSR slots; norm computed inline ----------
__global__ void scatter_k(const int* __restrict__ src, const int* __restrict__ dst,
                          const float* __restrict__ w, const float* __restrict__ dinv,
                          int* cursor, int2* __restrict__ csr) {
    int e = blockIdx.x * blockDim.x + threadIdx.x;
    if (e >= N_EDGES) return;
    int s = src[e], d = dst[e];
    int slot = atomicAdd(&cursor[d], 1);
    float nm = dinv[s] * w[e] * dinv[d];
    csr[slot] = make_int2(s, __float_as_int(nm));
}

// ---------- h = A @ W ; wave computes 4 rows, lane = col, W staged in LDS ----------
template<int K>
__global__ __launch_bounds__(256) void gemm_k(const float* __restrict__ A,
                                              const float* __restrict__ W,
                                              float* __restrict__ out) {
    __shared__ float Wl[K * EMB];
    for (int i = threadIdx.x; i < K * EMB; i += 256) Wl[i] = W[i];
    __syncthreads();
    int lane = threadIdx.x & 63;
    int wv = threadIdx.x >> 6;                 // 0..3
    int row0 = blockIdx.x * 16 + wv * 4;       // 16 rows per block; 50000 = 16*3125 exact
    const float* a = A + (long)row0 * K;
    float acc0 = 0.f, acc1 = 0.f, acc2 = 0.f, acc3 = 0.f;
#pragma unroll 4
    for (int k = 0; k < K; ++k) {
        float wk = Wl[k * EMB + lane];
        acc0 += a[k] * wk;
        acc1 += a[K + k] * wk;
        acc2 += a[2 * K + k] * wk;
        acc3 += a[3 * K + k] * wk;
    }
    long o = (long)row0 * EMB + lane;
    out[o] = acc0;
    out[o + EMB] = acc1;
    out[o + 2 * EMB] = acc2;
    out[o + 3 * EMB] = acc3;
}

// ---------- fused aggregation: self-loop + bias + CSR gather + tanh ----------
// one wave per node; lane = channel; register accumulation, single store
__global__ __launch_bounds__(256) void fused_agg_k(const float* __restrict__ h,
                                                   const int2* __restrict__ csr,
                                                   const int* __restrict__ row_start,
                                                   const float* __restrict__ dinv,
                                                   const float* __restrict__ b,
                                                   float* __restrict__ out) {
    int node = (blockIdx.x * blockDim.x + threadIdx.x) >> 6;
    int lane = threadIdx.x & 63;
    if (node >= N_NODES) return;
    float di = dinv[node];
    float acc = di * di * h[(long)node * EMB + lane] + b[lane];
    int e = row_start[node], end = row_start[node + 1];
    for (; e + 1 < end; e += 2) {
        int2 r0 = csr[e], r1 = csr[e + 1];
        float v0 = h[(long)r0.x * EMB + lane];
        float v1 = h[(long)r1.x * EMB + lane];
        acc += __int_as_float(r0.y) * v0;
        acc += __int_as_float(r1.y) * v1;
    }
    if (e < end) {
        int2 r0 = csr[e];
        acc += __int_as_float(r0.y) * h[(long)r0.x * EMB + lane];
    }
    out[(long)node * EMB + lane] = tanhf(acc);
}

// ---------- pooling ----------
__device__ inline int f2ord(float x) {
    int bb = __float_as_int(x);
    return bb >= 0 ? bb : (bb ^ 0x7fffffff);
}
__device__ inline float ord2f(int k) {
    return __int_as_float(k >= 0 ? k : (k ^ 0x7fffffff));
}

__global__ void pool_init_k(int* gmax, float* gsum, int* cnt) {
    int i = blockIdx.x * blockDim.x + threadIdx.x;
    if (i < N_GRAPHS * EMB) { gmax[i] = INT_MIN; gsum[i] = 0.f; }
    if (i < N_GRAPHS) cnt[i] = 0;
}

__global__ void pool_k(const float* __restrict__ h, const int* __restrict__ batch,
                       int* gmax, float* gsum, int* cnt) {
    int wave = (blockIdx.x * blockDim.x + threadIdx.x) >> 6;
    int lane = threadIdx.x & 63;
    int start = wave * POOL_CHUNK;
    if (start >= N_NODES) return;
    int end = min(start + POOL_CHUNK, N_NODES);
    int curg = batch[start];
    float mx = -INFINITY, sm = 0.f;
    int ct = 0;
    for (int i = start; i < end; ++i) {
        int g = batch[i];
        if (g != curg) {
            atomicMax(&gmax[curg * EMB + lane], f2ord(mx));
            atomicAdd(&gsum[curg * EMB + lane], sm);
            if (lane == 0) atomicAdd(&cnt[curg], ct);
            curg = g; mx = -INFINITY; sm = 0.f; ct = 0;
        }
        float v = h[(long)i * EMB + lane];
        mx = fmaxf(mx, v);
        sm += v;
        ++ct;
    }
    atomicMax(&gmax[curg * EMB + lane], f2ord(mx));
    atomicAdd(&gsum[curg * EMB + lane], sm);
    if (lane == 0) atomicAdd(&cnt[curg], ct);
}

__global__ void final_k(const int* __restrict__ gmax, const float* __restrict__ gsum,
                        const int* __restrict__ cnt, const float* __restrict__ Wout,
                        const float* __restrict__ bout, float* __restrict__ out) {
    int g = threadIdx.x;
    if (g >= N_GRAPHS) return;
    float c = fmaxf((float)cnt[g], 1.0f);
    float acc = bout[0];
    for (int ch = 0; ch < EMB; ++ch) {
        acc += ord2f(gmax[g * EMB + ch]) * Wout[ch]
             + (gsum[g * EMB + ch] / c) * Wout[EMB + ch];
    }
    out[g] = acc;
}

extern "C" void kernel_launch(void* const* d_in, const int* in_sizes, int n_in,
                              void* d_out, int out_size, void* d_ws, size_t ws_size,
                              hipStream_t stream) {
    const float* x         = (const float*)d_in[0];
    const int*   edge_idx  = (const int*)d_in[1];
    const float* edge_attr = (const float*)d_in[2];
    const int*   batch     = (const int*)d_in[3];
    const float* W0 = (const float*)d_in[4];
    const float* b0 = (const float*)d_in[5];
    const float* W1 = (const float*)d_in[6];
    const float* b1 = (const float*)d_in[7];
    const float* W2 = (const float*)d_in[8];
    const float* b2 = (const float*)d_in[9];
    const float* W3 = (const float*)d_in[10];
    const float* b3 = (const float*)d_in[11];
    const float* Wout = (const float*)d_in[12];
    const float* bout = (const float*)d_in[13];
    float* out = (float*)d_out;

    const int* src = edge_idx;            // edge_index[0]
    const int* dst = edge_idx + N_EDGES;  // edge_index[1]

    // workspace layout (~33 MB)
    char* ws = (char*)d_ws;
    float* dinv      = (float*)ws; ws += (size_t)N_NODES * sizeof(float);
    int*   counts    = (int*)ws;   ws += (size_t)N_NODES * sizeof(int);
    int*   row_start = (int*)ws;   ws += (size_t)(N_NODES + 1) * sizeof(int);
    int*   cursor    = (int*)ws;   ws += (size_t)N_NODES * sizeof(int);
    ws = (char*)(((uintptr_t)ws + 15) & ~(uintptr_t)15);
    int2*  csr       = (int2*)ws;  ws += (size_t)N_EDGES * sizeof(int2);
    float* bufL      = (float*)ws; ws += (size_t)N_NODES * EMB * sizeof(float);
    float* bufH      = (float*)ws; ws += (size_t)N_NODES * EMB * sizeof(float);
    int*   gmax      = (int*)ws;   ws += N_GRAPHS * EMB * sizeof(int);
    float* gsum      = (float*)ws; ws += N_GRAPHS * EMB * sizeof(float);
    int*   cnt       = (int*)ws;   ws += N_GRAPHS * sizeof(int);

    const int nodeB = (N_NODES + 255) / 256;
    const int edgeB = (N_EDGES + 255) / 256;
    const int waveB = (N_NODES * 64 + 255) / 256;  // one wave per node

    // CSR + norm precompute (shared by all 4 layers)
    init_k<<<nodeB, 256, 0, stream>>>(dinv, counts);
    hist_k<<<edgeB, 256, 0, stream>>>(dst, edge_attr, dinv, counts);
    dinv_k<<<nodeB, 256, 0, stream>>>(dinv);
    scan_k<<<1, SCAN_T, 0, stream>>>(counts, row_start, cursor);
    scatter_k<<<edgeB, 256, 0, stream>>>(src, dst, edge_attr, dinv, cursor, csr);

    const float* Wl[4] = {W0, W1, W2, W3};
    const float* bl[4] = {b0, b1, b2, b3};
    for (int l = 0; l < 4; ++l) {
        if (l == 0) gemm_k<IN_CH><<<3125, 256, 0, stream>>>(x, Wl[0], bufL);
        else        gemm_k<EMB>  <<<3125, 256, 0, stream>>>(bufH, Wl[l], bufL);
        fused_agg_k<<<waveB, 256, 0, stream>>>(bufL, csr, row_start, dinv, bl[l], bufH);
    }

    pool_init_k<<<(N_GRAPHS * EMB + 255) / 256, 256, 0, stream>>>(gmax, gsum, cnt);
    int poolWaves = (N_NODES + POOL_CHUNK - 1) / POOL_CHUNK;
    pool_k<<<(poolWaves * 64 + 255) / 256, 256, 0, stream>>>(bufH, batch, gmax, gsum, cnt);
    final_k<<<1, 64, 0, stream>>>(gmax, gsum, cnt, Wout, bout, out);
}

// Round 3
// 684.010 us; speedup vs baseline: 1.7140x; 1.1582x over previous
//
#include <hip/hip_runtime.h>
#include <math.h>
#include <limits.h>

#define N_NODES 50000
#define N_EDGES 800000
#define N_GRAPHS 64
#define IN_CH 128
#define EMB 64
#define POOL_CHUNK 256

// ---------- init: deg=1 (self-loop), counts=0, total=0 ----------
__global__ void init_k(float* deg, int* counts, int* total) {
    int i = blockIdx.x * blockDim.x + threadIdx.x;
    if (i < N_NODES) { deg[i] = 1.0f; counts[i] = 0; }
    if (i == 0) *total = 0;
}

// ---------- fused histogram: in-degree count + weighted degree ----------
__global__ void hist_k(const int* __restrict__ dst, const float* __restrict__ w,
                       float* deg, int* counts) {
    int e = blockIdx.x * blockDim.x + threadIdx.x;
    if (e >= N_EDGES) return;
    int d = dst[e];
    atomicAdd(&counts[d], 1);
    atomicAdd(&deg[d], w[e]);
}

__global__ void dinv_k(float* deg) {
    int i = blockIdx.x * blockDim.x + threadIdx.x;
    if (i < N_NODES) {
        float d = deg[i];
        deg[i] = d > 0.f ? rsqrtf(d) : 0.f;  // in-place: deg -> dinv
    }
}

// ---------- CSR range allocation: wave-scan + one atomic per wave ----------
// Node ranges land in arbitrary order (run-to-run nondeterministic placement),
// but each node's range is contiguous and sums are order-independent -> results
// are deterministic.
__global__ void alloc_k(const int* __restrict__ counts, int* __restrict__ row_start,
                        int* __restrict__ cursor, int* total) {
    int i = blockIdx.x * blockDim.x + threadIdx.x;
    int lane = threadIdx.x & 63;
    int c = (i < N_NODES) ? counts[i] : 0;
    // 64-lane inclusive scan
    int inc = c;
    for (int off = 1; off < 64; off <<= 1) {
        int v = __shfl_up(inc, off);
        if (lane >= off) inc += v;
    }
    int base;
    if (lane == 63) base = atomicAdd(total, inc);
    base = __shfl(base, 63);
    int excl = base + inc - c;
    if (i < N_NODES) { row_start[i] = excl; cursor[i] = excl; }
}

// ---------- scatter edges into CSR slots; norm computed inline ----------
__global__ void scatter_k(const int* __restrict__ src, const int* __restrict__ dst,
                          const float* __restrict__ w, const float* __restrict__ dinv,
                          int* cursor, int2* __restrict__ csr) {
    int e = blockIdx.x * blockDim.x + threadIdx.x;
    if (e >= N_EDGES) return;
    int s = src[e], d = dst[e];
    int slot = atomicAdd(&cursor[d], 1);
    float nm = dinv[s] * w[e] * dinv[d];
    csr[slot] = make_int2(s, __float_as_int(nm));
}

// ---------- h = A @ W ; wave computes 4 rows, lane = col, W staged in LDS ----------
template<int K>
__global__ __launch_bounds__(256) void gemm_k(const float* __restrict__ A,
                                              const float* __restrict__ W,
                                              float* __restrict__ out) {
    __shared__ float Wl[K * EMB];
    for (int i = threadIdx.x; i < K * EMB; i += 256) Wl[i] = W[i];
    __syncthreads();
    int lane = threadIdx.x & 63;
    int wv = threadIdx.x >> 6;                 // 0..3
    int row0 = blockIdx.x * 16 + wv * 4;       // 16 rows per block; 50000 = 16*3125 exact
    const float* a = A + (long)row0 * K;
    float acc0 = 0.f, acc1 = 0.f, acc2 = 0.f, acc3 = 0.f;
#pragma unroll 4
    for (int k = 0; k < K; ++k) {
        float wk = Wl[k * EMB + lane];
        acc0 += a[k] * wk;
        acc1 += a[K + k] * wk;
        acc2 += a[2 * K + k] * wk;
        acc3 += a[3 * K + k] * wk;
    }
    long o = (long)row0 * EMB + lane;
    out[o] = acc0;
    out[o + EMB] = acc1;
    out[o + 2 * EMB] = acc2;
    out[o + 3 * EMB] = acc3;
}

// ---------- fused aggregation: self-loop + bias + CSR gather + tanh ----------
// one wave per node; lane = channel; register accumulation, single store
__global__ __launch_bounds__(256) void fused_agg_k(const float* __restrict__ h,
                                                   const int2* __restrict__ csr,
                                                   const int* __restrict__ row_start,
                                                   const int* __restrict__ counts,
                                                   const float* __restrict__ dinv,
                                                   const float* __restrict__ b,
                                                   float* __restrict__ out) {
    int node = (blockIdx.x * blockDim.x + threadIdx.x) >> 6;
    int lane = threadIdx.x & 63;
    if (node >= N_NODES) return;
    float di = dinv[node];
    float acc = di * di * h[(long)node * EMB + lane] + b[lane];
    int e = row_start[node];
    int end = e + counts[node];
    for (; e + 1 < end; e += 2) {
        int2 r0 = csr[e], r1 = csr[e + 1];
        float v0 = h[(long)r0.x * EMB + lane];
        float v1 = h[(long)r1.x * EMB + lane];
        acc += __int_as_float(r0.y) * v0;
        acc += __int_as_float(r1.y) * v1;
    }
    if (e < end) {
        int2 r0 = csr[e];
        acc += __int_as_float(r0.y) * h[(long)r0.x * EMB + lane];
    }
    out[(long)node * EMB + lane] = tanhf(acc);
}

// ---------- pooling ----------
__device__ inline int f2ord(float x) {
    int bb = __float_as_int(x);
    return bb >= 0 ? bb : (bb ^ 0x7fffffff);
}
__device__ inline float ord2f(int k) {
    return __int_as_float(k >= 0 ? k : (k ^ 0x7fffffff));
}

__global__ void pool_init_k(int* gmax, float* gsum, int* cnt) {
    int i = blockIdx.x * blockDim.x + threadIdx.x;
    if (i < N_GRAPHS * EMB) { gmax[i] = INT_MIN; gsum[i] = 0.f; }
    if (i < N_GRAPHS) cnt[i] = 0;
}

__global__ void pool_k(const float* __restrict__ h, const int* __restrict__ batch,
                       int* gmax, float* gsum, int* cnt) {
    int wave = (blockIdx.x * blockDim.x + threadIdx.x) >> 6;
    int lane = threadIdx.x & 63;
    int start = wave * POOL_CHUNK;
    if (start >= N_NODES) return;
    int end = min(start + POOL_CHUNK, N_NODES);
    int curg = batch[start];
    float mx = -INFINITY, sm = 0.f;
    int ct = 0;
    for (int i = start; i < end; ++i) {
        int g = batch[i];
        if (g != curg) {
            atomicMax(&gmax[curg * EMB + lane], f2ord(mx));
            atomicAdd(&gsum[curg * EMB + lane], sm);
            if (lane == 0) atomicAdd(&cnt[curg], ct);
            curg = g; mx = -INFINITY; sm = 0.f; ct = 0;
        }
        float v = h[(long)i * EMB + lane];
        mx = fmaxf(mx, v);
        sm += v;
        ++ct;
    }
    atomicMax(&gmax[curg * EMB + lane], f2ord(mx));
    atomicAdd(&gsum[curg * EMB + lane], sm);
    if (lane == 0) atomicAdd(&cnt[curg], ct);
}

__global__ void final_k(const int* __restrict__ gmax, const float* __restrict__ gsum,
                        const int* __restrict__ cnt, const float* __restrict__ Wout,
                        const float* __restrict__ bout, float* __restrict__ out) {
    int g = threadIdx.x;
    if (g >= N_GRAPHS) return;
    float c = fmaxf((float)cnt[g], 1.0f);
    float acc = bout[0];
    for (int ch = 0; ch < EMB; ++ch) {
        acc += ord2f(gmax[g * EMB + ch]) * Wout[ch]
             + (gsum[g * EMB + ch] / c) * Wout[EMB + ch];
    }
    out[g] = acc;
}

extern "C" void kernel_launch(void* const* d_in, const int* in_sizes, int n_in,
                              void* d_out, int out_size, void* d_ws, size_t ws_size,
                              hipStream_t stream) {
    const float* x         = (const float*)d_in[0];
    const int*   edge_idx  = (const int*)d_in[1];
    const float* edge_attr = (const float*)d_in[2];
    const int*   batch     = (const int*)d_in[3];
    const float* W0 = (const float*)d_in[4];
    const float* b0 = (const float*)d_in[5];
    const float* W1 = (const float*)d_in[6];
    const float* b1 = (const float*)d_in[7];
    const float* W2 = (const float*)d_in[8];
    const float* b2 = (const float*)d_in[9];
    const float* W3 = (const float*)d_in[10];
    const float* b3 = (const float*)d_in[11];
    const float* Wout = (const float*)d_in[12];
    const float* bout = (const float*)d_in[13];
    float* out = (float*)d_out;

    const int* src = edge_idx;            // edge_index[0]
    const int* dst = edge_idx + N_EDGES;  // edge_index[1]

    // workspace layout (~33 MB)
    char* ws = (char*)d_ws;
    float* dinv      = (float*)ws; ws += (size_t)N_NODES * sizeof(float);
    int*   counts    = (int*)ws;   ws += (size_t)N_NODES * sizeof(int);
    int*   row_start = (int*)ws;   ws += (size_t)N_NODES * sizeof(int);
    int*   cursor    = (int*)ws;   ws += (size_t)N_NODES * sizeof(int);
    int*   total     = (int*)ws;   ws += 4 * sizeof(int);  // keep 16B alignment
    int2*  csr       = (int2*)ws;  ws += (size_t)N_EDGES * sizeof(int2);
    float* bufL      = (float*)ws; ws += (size_t)N_NODES * EMB * sizeof(float);
    float* bufH      = (float*)ws; ws += (size_t)N_NODES * EMB * sizeof(float);
    int*   gmax      = (int*)ws;   ws += N_GRAPHS * EMB * sizeof(int);
    float* gsum      = (float*)ws; ws += N_GRAPHS * EMB * sizeof(float);
    int*   cnt       = (int*)ws;   ws += N_GRAPHS * sizeof(int);

    const int nodeB = (N_NODES + 255) / 256;
    const int edgeB = (N_EDGES + 255) / 256;
    const int waveB = (N_NODES * 64 + 255) / 256;  // one wave per node

    // CSR + norm precompute (shared by all 4 layers)
    init_k<<<nodeB, 256, 0, stream>>>(dinv, counts, total);
    hist_k<<<edgeB, 256, 0, stream>>>(dst, edge_attr, dinv, counts);
    dinv_k<<<nodeB, 256, 0, stream>>>(dinv);
    alloc_k<<<nodeB, 256, 0, stream>>>(counts, row_start, cursor, total);
    scatter_k<<<edgeB, 256, 0, stream>>>(src, dst, edge_attr, dinv, cursor, csr);

    const float* Wl[4] = {W0, W1, W2, W3};
    const float* bl[4] = {b0, b1, b2, b3};
    for (int l = 0; l < 4; ++l) {
        if (l == 0) gemm_k<IN_CH><<<3125, 256, 0, stream>>>(x, Wl[0], bufL);
        else        gemm_k<EMB>  <<<3125, 256, 0, stream>>>(bufH, Wl[l], bufL);
        fused_agg_k<<<waveB, 256, 0, stream>>>(bufL, csr, row_start, counts, dinv, bl[l], bufH);
    }

    pool_init_k<<<(N_GRAPHS * EMB + 255) / 256, 256, 0, stream>>>(gmax, gsum, cnt);
    int poolWaves = (N_NODES + POOL_CHUNK - 1) / POOL_CHUNK;
    pool_k<<<(poolWaves * 64 + 255) / 256, 256, 0, stream>>>(bufH, batch, gmax, gsum, cnt);
    final_k<<<1, 64, 0, stream>>>(gmax, gsum, cnt, Wout, bout, out);
}

// Round 4
// 568.674 us; speedup vs baseline: 2.0616x; 1.2028x over previous
//
#include <hip/hip_runtime.h>
#include <math.h>
#include <limits.h>

#define N_NODES 50000
#define N_EDGES 800000
#define N_GRAPHS 64
#define IN_CH 128
#define EMB 64
#define POOL_CHUNK 16   // 50000 = 16 * 3125 exactly; 3125 waves -> ~12 waves/CU

// ---------- init: deg=1 (self-loop), counts=0, total=0 ----------
__global__ void init_k(float* deg, int* counts, int* total) {
    int i = blockIdx.x * blockDim.x + threadIdx.x;
    if (i < N_NODES) { deg[i] = 1.0f; counts[i] = 0; }
    if (i == 0) *total = 0;
}

// ---------- fused histogram: in-degree count + weighted degree ----------
__global__ void hist_k(const int* __restrict__ dst, const float* __restrict__ w,
                       float* deg, int* counts) {
    int e = blockIdx.x * blockDim.x + threadIdx.x;
    if (e >= N_EDGES) return;
    int d = dst[e];
    atomicAdd(&counts[d], 1);
    atomicAdd(&deg[d], w[e]);
}

__global__ void dinv_k(float* deg) {
    int i = blockIdx.x * blockDim.x + threadIdx.x;
    if (i < N_NODES) {
        float d = deg[i];
        deg[i] = d > 0.f ? rsqrtf(d) : 0.f;  // in-place: deg -> dinv
    }
}

// ---------- CSR range allocation: wave-scan + one atomic per wave ----------
__global__ void alloc_k(const int* __restrict__ counts, int* __restrict__ row_start,
                        int* __restrict__ cursor, int* total) {
    int i = blockIdx.x * blockDim.x + threadIdx.x;
    int lane = threadIdx.x & 63;
    int c = (i < N_NODES) ? counts[i] : 0;
    int inc = c;
    for (int off = 1; off < 64; off <<= 1) {
        int v = __shfl_up(inc, off);
        if (lane >= off) inc += v;
    }
    int base;
    if (lane == 63) base = atomicAdd(total, inc);
    base = __shfl(base, 63);
    int excl = base + inc - c;
    if (i < N_NODES) { row_start[i] = excl; cursor[i] = excl; }
}

// ---------- scatter edges into CSR slots; norm computed inline ----------
__global__ void scatter_k(const int* __restrict__ src, const int* __restrict__ dst,
                          const float* __restrict__ w, const float* __restrict__ dinv,
                          int* cursor, int2* __restrict__ csr) {
    int e = blockIdx.x * blockDim.x + threadIdx.x;
    if (e >= N_EDGES) return;
    int s = src[e], d = dst[e];
    int slot = atomicAdd(&cursor[d], 1);
    float nm = dinv[s] * w[e] * dinv[d];
    csr[slot] = make_int2(s, __float_as_int(nm));
}

// ---------- h = A @ W ; wave computes 4 rows, lane = col, W staged in LDS ----------
template<int K>
__global__ __launch_bounds__(256) void gemm_k(const float* __restrict__ A,
                                              const float* __restrict__ W,
                                              float* __restrict__ out) {
    __shared__ float Wl[K * EMB];
    for (int i = threadIdx.x; i < K * EMB; i += 256) Wl[i] = W[i];
    __syncthreads();
    int lane = threadIdx.x & 63;
    int wv = threadIdx.x >> 6;                 // 0..3
    int row0 = blockIdx.x * 16 + wv * 4;       // 16 rows per block; 50000 = 16*3125 exact
    const float* a = A + (long)row0 * K;
    float acc0 = 0.f, acc1 = 0.f, acc2 = 0.f, acc3 = 0.f;
#pragma unroll 4
    for (int k = 0; k < K; ++k) {
        float wk = Wl[k * EMB + lane];
        acc0 += a[k] * wk;
        acc1 += a[K + k] * wk;
        acc2 += a[2 * K + k] * wk;
        acc3 += a[3 * K + k] * wk;
    }
    long o = (long)row0 * EMB + lane;
    out[o] = acc0;
    out[o + EMB] = acc1;
    out[o + 2 * EMB] = acc2;
    out[o + 3 * EMB] = acc3;
}

// ---------- fused aggregation: self-loop + bias + CSR gather + tanh ----------
// one wave per node; lane = channel; 4 independent gathers in flight
__global__ __launch_bounds__(256) void fused_agg_k(const float* __restrict__ h,
                                                   const int2* __restrict__ csr,
                                                   const int* __restrict__ row_start,
                                                   const int* __restrict__ counts,
                                                   const float* __restrict__ dinv,
                                                   const float* __restrict__ b,
                                                   float* __restrict__ out) {
    int node = (blockIdx.x * blockDim.x + threadIdx.x) >> 6;
    int lane = threadIdx.x & 63;
    if (node >= N_NODES) return;
    float di = dinv[node];
    float acc = di * di * h[(long)node * EMB + lane] + b[lane];
    int e = row_start[node];
    int end = e + counts[node];
    for (; e + 3 < end; e += 4) {
        int2 r0 = csr[e], r1 = csr[e + 1], r2 = csr[e + 2], r3 = csr[e + 3];
        float v0 = h[(long)r0.x * EMB + lane];
        float v1 = h[(long)r1.x * EMB + lane];
        float v2 = h[(long)r2.x * EMB + lane];
        float v3 = h[(long)r3.x * EMB + lane];
        acc += __int_as_float(r0.y) * v0;
        acc += __int_as_float(r1.y) * v1;
        acc += __int_as_float(r2.y) * v2;
        acc += __int_as_float(r3.y) * v3;
    }
    for (; e < end; ++e) {
        int2 r0 = csr[e];
        acc += __int_as_float(r0.y) * h[(long)r0.x * EMB + lane];
    }
    out[(long)node * EMB + lane] = tanhf(acc);
}

// ---------- pooling ----------
__device__ inline int f2ord(float x) {
    int bb = __float_as_int(x);
    return bb >= 0 ? bb : (bb ^ 0x7fffffff);
}
__device__ inline float ord2f(int k) {
    return __int_as_float(k >= 0 ? k : (k ^ 0x7fffffff));
}

__global__ void pool_init_k(int* gmax, float* gsum, int* cnt) {
    int i = blockIdx.x * blockDim.x + threadIdx.x;
    if (i < N_GRAPHS * EMB) { gmax[i] = INT_MIN; gsum[i] = 0.f; }
    if (i < N_GRAPHS) cnt[i] = 0;
}

// wave = 16 contiguous nodes (batch sorted); lane = channel.
// All 16 h-rows preloaded (independent loads); batch broadcast via shfl.
__global__ __launch_bounds__(256) void pool_k(const float* __restrict__ h,
                                              const int* __restrict__ batch,
                                              int* gmax, float* gsum, int* cnt) {
    int wave = (blockIdx.x * blockDim.x + threadIdx.x) >> 6;
    int lane = threadIdx.x & 63;
    int start = wave * POOL_CHUNK;
    if (start >= N_NODES) return;   // 50000 % 16 == 0 -> full chunks always
    int bsel = (lane < POOL_CHUNK) ? batch[start + lane] : 0;
    float v[POOL_CHUNK];
#pragma unroll
    for (int i = 0; i < POOL_CHUNK; ++i)
        v[i] = h[(long)(start + i) * EMB + lane];
    int curg = __shfl(bsel, 0);
    float mx = -INFINITY, sm = 0.f;
    int ct = 0;
#pragma unroll
    for (int i = 0; i < POOL_CHUNK; ++i) {
        int g = __shfl(bsel, i);
        if (g != curg) {
            atomicMax(&gmax[curg * EMB + lane], f2ord(mx));
            atomicAdd(&gsum[curg * EMB + lane], sm);
            if (lane == 0) atomicAdd(&cnt[curg], ct);
            curg = g; mx = -INFINITY; sm = 0.f; ct = 0;
        }
        mx = fmaxf(mx, v[i]);
        sm += v[i];
        ++ct;
    }
    atomicMax(&gmax[curg * EMB + lane], f2ord(mx));
    atomicAdd(&gsum[curg * EMB + lane], sm);
    if (lane == 0) atomicAdd(&cnt[curg], ct);
}

__global__ void final_k(const int* __restrict__ gmax, const float* __restrict__ gsum,
                        const int* __restrict__ cnt, const float* __restrict__ Wout,
                        const float* __restrict__ bout, float* __restrict__ out) {
    int g = threadIdx.x;
    if (g >= N_GRAPHS) return;
    float c = fmaxf((float)cnt[g], 1.0f);
    float acc = bout[0];
    for (int ch = 0; ch < EMB; ++ch) {
        acc += ord2f(gmax[g * EMB + ch]) * Wout[ch]
             + (gsum[g * EMB + ch] / c) * Wout[EMB + ch];
    }
    out[g] = acc;
}

extern "C" void kernel_launch(void* const* d_in, const int* in_sizes, int n_in,
                              void* d_out, int out_size, void* d_ws, size_t ws_size,
                              hipStream_t stream) {
    const float* x         = (const float*)d_in[0];
    const int*   edge_idx  = (const int*)d_in[1];
    const float* edge_attr = (const float*)d_in[2];
    const int*   batch     = (const int*)d_in[3];
    const float* W0 = (const float*)d_in[4];
    const float* b0 = (const float*)d_in[5];
    const float* W1 = (const float*)d_in[6];
    const float* b1 = (const float*)d_in[7];
    const float* W2 = (const float*)d_in[8];
    const float* b2 = (const float*)d_in[9];
    const float* W3 = (const float*)d_in[10];
    const float* b3 = (const float*)d_in[11];
    const float* Wout = (const float*)d_in[12];
    const float* bout = (const float*)d_in[13];
    float* out = (float*)d_out;

    const int* src = edge_idx;            // edge_index[0]
    const int* dst = edge_idx + N_EDGES;  // edge_index[1]

    // workspace layout (~33 MB)
    char* ws = (char*)d_ws;
    float* dinv      = (float*)ws; ws += (size_t)N_NODES * sizeof(float);
    int*   counts    = (int*)ws;   ws += (size_t)N_NODES * sizeof(int);
    int*   row_start = (int*)ws;   ws += (size_t)N_NODES * sizeof(int);
    int*   cursor    = (int*)ws;   ws += (size_t)N_NODES * sizeof(int);
    int*   total     = (int*)ws;   ws += 4 * sizeof(int);  // keep 16B alignment
    int2*  csr       = (int2*)ws;  ws += (size_t)N_EDGES * sizeof(int2);
    float* bufL      = (float*)ws; ws += (size_t)N_NODES * EMB * sizeof(float);
    float* bufH      = (float*)ws; ws += (size_t)N_NODES * EMB * sizeof(float);
    int*   gmax      = (int*)ws;   ws += N_GRAPHS * EMB * sizeof(int);
    float* gsum      = (float*)ws; ws += N_GRAPHS * EMB * sizeof(float);
    int*   cnt       = (int*)ws;   ws += N_GRAPHS * sizeof(int);

    const int nodeB = (N_NODES + 255) / 256;
    const int edgeB = (N_EDGES + 255) / 256;
    const int waveB = (N_NODES * 64 + 255) / 256;  // one wave per node

    // CSR + norm precompute (shared by all 4 layers)
    init_k<<<nodeB, 256, 0, stream>>>(dinv, counts, total);
    hist_k<<<edgeB, 256, 0, stream>>>(dst, edge_attr, dinv, counts);
    dinv_k<<<nodeB, 256, 0, stream>>>(dinv);
    alloc_k<<<nodeB, 256, 0, stream>>>(counts, row_start, cursor, total);
    scatter_k<<<edgeB, 256, 0, stream>>>(src, dst, edge_attr, dinv, cursor, csr);

    const float* Wl[4] = {W0, W1, W2, W3};
    const float* bl[4] = {b0, b1, b2, b3};
    for (int l = 0; l < 4; ++l) {
        if (l == 0) gemm_k<IN_CH><<<3125, 256, 0, stream>>>(x, Wl[0], bufL);
        else        gemm_k<EMB>  <<<3125, 256, 0, stream>>>(bufH, Wl[l], bufL);
        fused_agg_k<<<waveB, 256, 0, stream>>>(bufL, csr, row_start, counts, dinv, bl[l], bufH);
    }

    pool_init_k<<<(N_GRAPHS * EMB + 255) / 256, 256, 0, stream>>>(gmax, gsum, cnt);
    int poolWaves = (N_NODES + POOL_CHUNK - 1) / POOL_CHUNK;
    pool_k<<<(poolWaves * 64 + 255) / 256, 256, 0, stream>>>(bufH, batch, gmax, gsum, cnt);
    final_k<<<1, 64, 0, stream>>>(gmax, gsum, cnt, Wout, bout, out);
}

// Round 5
// 515.730 us; speedup vs baseline: 2.2733x; 1.1027x over previous
//
#include <hip/hip_runtime.h>
#include <math.h>
#include <limits.h>

#define N_NODES 50000
#define N_EDGES 800000
#define N_GRAPHS 64
#define IN_CH 128
#define EMB 64
#define POOL_CHUNK 16   // 50000 = 16 * 3125 exactly; 3125 waves -> ~12 waves/CU

// ---------- init: counts=0, total=0, pool accumulators ----------
__global__ void init_k(int* counts, int* total, int* gmax, float* gsum, int* cnt) {
    int i = blockIdx.x * blockDim.x + threadIdx.x;
    if (i < N_NODES) counts[i] = 0;
    if (i == 0) *total = 0;
    if (i < N_GRAPHS * EMB) { gmax[i] = INT_MIN; gsum[i] = 0.f; }
    if (i < N_GRAPHS) cnt[i] = 0;
}

// ---------- histogram: in-degree count; returned old value = stable slot ----------
__global__ void hist_k(const int* __restrict__ dst, int* counts,
                       int* __restrict__ slot_in) {
    int e = blockIdx.x * blockDim.x + threadIdx.x;
    if (e >= N_EDGES) return;
    slot_in[e] = atomicAdd(&counts[dst[e]], 1);
}

// ---------- CSR range allocation: wave-scan + one atomic per wave ----------
__global__ void alloc_k(const int* __restrict__ counts, int* __restrict__ row_start,
                        int* total) {
    int i = blockIdx.x * blockDim.x + threadIdx.x;
    int lane = threadIdx.x & 63;
    int c = (i < N_NODES) ? counts[i] : 0;
    int inc = c;
    for (int off = 1; off < 64; off <<= 1) {
        int v = __shfl_up(inc, off);
        if (lane >= off) inc += v;
    }
    int base;
    if (lane == 63) base = atomicAdd(total, inc);
    base = __shfl(base, 63);
    if (i < N_NODES) row_start[i] = base + inc - c;
}

// ---------- scatter edges into CSR slots (atomic-free); store (src, raw w) ----------
__global__ void scatter_k(const int* __restrict__ src, const int* __restrict__ dst,
                          const float* __restrict__ w, const int* __restrict__ slot_in,
                          const int* __restrict__ row_start, int2* __restrict__ csr) {
    int e = blockIdx.x * blockDim.x + threadIdx.x;
    if (e >= N_EDGES) return;
    int d = dst[e];
    int slot = row_start[d] + slot_in[e];
    csr[slot] = make_int2(src[e], __float_as_int(w[e]));
}

// ---------- per-node weighted degree (wave reduction over CSR range) -> dinv ----------
__global__ __launch_bounds__(256) void deg_dinv_k(const int2* __restrict__ csr,
                                                  const int* __restrict__ row_start,
                                                  const int* __restrict__ counts,
                                                  float* __restrict__ dinv) {
    int node = (blockIdx.x * blockDim.x + threadIdx.x) >> 6;
    int lane = threadIdx.x & 63;
    if (node >= N_NODES) return;
    int beg = row_start[node], n = counts[node];
    float s = 0.f;
    for (int i = lane; i < n; i += 64) s += __int_as_float(csr[beg + i].y);
    for (int off = 32; off > 0; off >>= 1) s += __shfl_down(s, off);
    if (lane == 0) {
        float d = 1.0f + s;  // self-loop weight 1
        dinv[node] = d > 0.f ? rsqrtf(d) : 0.f;
    }
}

// ---------- rewrite csr.y: raw w -> norm = dinv[s] * w * dinv[d] ----------
__global__ __launch_bounds__(256) void normfix_k(int2* __restrict__ csr,
                                                 const int* __restrict__ row_start,
                                                 const int* __restrict__ counts,
                                                 const float* __restrict__ dinv) {
    int node = (blockIdx.x * blockDim.x + threadIdx.x) >> 6;
    int lane = threadIdx.x & 63;
    if (node >= N_NODES) return;
    int beg = row_start[node], n = counts[node];
    float dd = dinv[node];
    for (int i = lane; i < n; i += 64) {
        int2 r = csr[beg + i];
        float nm = dinv[r.x] * __int_as_float(r.y) * dd;
        csr[beg + i] = make_int2(r.x, __float_as_int(nm));
    }
}

// ---------- h = A @ W ; wave computes 4 rows, lane = col, W staged in LDS ----------
template<int K>
__global__ __launch_bounds__(256) void gemm_k(const float* __restrict__ A,
                                              const float* __restrict__ W,
                                              float* __restrict__ out) {
    __shared__ float Wl[K * EMB];
    for (int i = threadIdx.x; i < K * EMB; i += 256) Wl[i] = W[i];
    __syncthreads();
    int lane = threadIdx.x & 63;
    int wv = threadIdx.x >> 6;                 // 0..3
    int row0 = blockIdx.x * 16 + wv * 4;       // 16 rows per block; 50000 = 16*3125 exact
    const float* a = A + (long)row0 * K;
    float acc0 = 0.f, acc1 = 0.f, acc2 = 0.f, acc3 = 0.f;
#pragma unroll 4
    for (int k = 0; k < K; ++k) {
        float wk = Wl[k * EMB + lane];
        acc0 += a[k] * wk;
        acc1 += a[K + k] * wk;
        acc2 += a[2 * K + k] * wk;
        acc3 += a[3 * K + k] * wk;
    }
    long o = (long)row0 * EMB + lane;
    out[o] = acc0;
    out[o + EMB] = acc1;
    out[o + 2 * EMB] = acc2;
    out[o + 3 * EMB] = acc3;
}

// ---------- fused aggregation: self-loop + bias + CSR gather + tanh ----------
__global__ __launch_bounds__(256) void fused_agg_k(const float* __restrict__ h,
                                                   const int2* __restrict__ csr,
                                                   const int* __restrict__ row_start,
                                                   const int* __restrict__ counts,
                                                   const float* __restrict__ dinv,
                                                   const float* __restrict__ b,
                                                   float* __restrict__ out) {
    int node = (blockIdx.x * blockDim.x + threadIdx.x) >> 6;
    int lane = threadIdx.x & 63;
    if (node >= N_NODES) return;
    float di = dinv[node];
    float acc = di * di * h[(long)node * EMB + lane] + b[lane];
    int e = row_start[node];
    int end = e + counts[node];
    for (; e + 3 < end; e += 4) {
        int2 r0 = csr[e], r1 = csr[e + 1], r2 = csr[e + 2], r3 = csr[e + 3];
        float v0 = h[(long)r0.x * EMB + lane];
        float v1 = h[(long)r1.x * EMB + lane];
        float v2 = h[(long)r2.x * EMB + lane];
        float v3 = h[(long)r3.x * EMB + lane];
        acc += __int_as_float(r0.y) * v0;
        acc += __int_as_float(r1.y) * v1;
        acc += __int_as_float(r2.y) * v2;
        acc += __int_as_float(r3.y) * v3;
    }
    for (; e < end; ++e) {
        int2 r0 = csr[e];
        acc += __int_as_float(r0.y) * h[(long)r0.x * EMB + lane];
    }
    out[(long)node * EMB + lane] = tanhf(acc);
}

// ---------- pooling ----------
__device__ inline int f2ord(float x) {
    int bb = __float_as_int(x);
    return bb >= 0 ? bb : (bb ^ 0x7fffffff);
}
__device__ inline float ord2f(int k) {
    return __int_as_float(k >= 0 ? k : (k ^ 0x7fffffff));
}

// wave = 16 contiguous nodes (batch sorted); lane = channel.
__global__ __launch_bounds__(256) void pool_k(const float* __restrict__ h,
                                              const int* __restrict__ batch,
                                              int* gmax, float* gsum, int* cnt) {
    int wave = (blockIdx.x * blockDim.x + threadIdx.x) >> 6;
    int lane = threadIdx.x & 63;
    int start = wave * POOL_CHUNK;
    if (start >= N_NODES) return;   // 50000 % 16 == 0 -> full chunks always
    int bsel = (lane < POOL_CHUNK) ? batch[start + lane] : 0;
    float v[POOL_CHUNK];
#pragma unroll
    for (int i = 0; i < POOL_CHUNK; ++i)
        v[i] = h[(long)(start + i) * EMB + lane];
    int curg = __shfl(bsel, 0);
    float mx = -INFINITY, sm = 0.f;
    int ct = 0;
#pragma unroll
    for (int i = 0; i < POOL_CHUNK; ++i) {
        int g = __shfl(bsel, i);
        if (g != curg) {
            atomicMax(&gmax[curg * EMB + lane], f2ord(mx));
            atomicAdd(&gsum[curg * EMB + lane], sm);
            if (lane == 0) atomicAdd(&cnt[curg], ct);
            curg = g; mx = -INFINITY; sm = 0.f; ct = 0;
        }
        mx = fmaxf(mx, v[i]);
        sm += v[i];
        ++ct;
    }
    atomicMax(&gmax[curg * EMB + lane], f2ord(mx));
    atomicAdd(&gsum[curg * EMB + lane], sm);
    if (lane == 0) atomicAdd(&cnt[curg], ct);
}

__global__ void final_k(const int* __restrict__ gmax, const float* __restrict__ gsum,
                        const int* __restrict__ cnt, const float* __restrict__ Wout,
                        const float* __restrict__ bout, float* __restrict__ out) {
    int g = threadIdx.x;
    if (g >= N_GRAPHS) return;
    float c = fmaxf((float)cnt[g], 1.0f);
    float acc = bout[0];
    for (int ch = 0; ch < EMB; ++ch) {
        acc += ord2f(gmax[g * EMB + ch]) * Wout[ch]
             + (gsum[g * EMB + ch] / c) * Wout[EMB + ch];
    }
    out[g] = acc;
}

extern "C" void kernel_launch(void* const* d_in, const int* in_sizes, int n_in,
                              void* d_out, int out_size, void* d_ws, size_t ws_size,
                              hipStream_t stream) {
    const float* x         = (const float*)d_in[0];
    const int*   edge_idx  = (const int*)d_in[1];
    const float* edge_attr = (const float*)d_in[2];
    const int*   batch     = (const int*)d_in[3];
    const float* W0 = (const float*)d_in[4];
    const float* b0 = (const float*)d_in[5];
    const float* W1 = (const float*)d_in[6];
    const float* b1 = (const float*)d_in[7];
    const float* W2 = (const float*)d_in[8];
    const float* b2 = (const float*)d_in[9];
    const float* W3 = (const float*)d_in[10];
    const float* b3 = (const float*)d_in[11];
    const float* Wout = (const float*)d_in[12];
    const float* bout = (const float*)d_in[13];
    float* out = (float*)d_out;

    const int* src = edge_idx;            // edge_index[0]
    const int* dst = edge_idx + N_EDGES;  // edge_index[1]

    // workspace layout (~36 MB)
    char* ws = (char*)d_ws;
    float* dinv      = (float*)ws; ws += (size_t)N_NODES * sizeof(float);
    int*   counts    = (int*)ws;   ws += (size_t)N_NODES * sizeof(int);
    int*   row_start = (int*)ws;   ws += (size_t)N_NODES * sizeof(int);
    int*   slot_in   = (int*)ws;   ws += (size_t)N_EDGES * sizeof(int);
    int*   total     = (int*)ws;   ws += 4 * sizeof(int);  // keep 16B alignment
    int2*  csr       = (int2*)ws;  ws += (size_t)N_EDGES * sizeof(int2);
    float* bufL      = (float*)ws; ws += (size_t)N_NODES * EMB * sizeof(float);
    float* bufH      = (float*)ws; ws += (size_t)N_NODES * EMB * sizeof(float);
    int*   gmax      = (int*)ws;   ws += N_GRAPHS * EMB * sizeof(int);
    float* gsum      = (float*)ws; ws += N_GRAPHS * EMB * sizeof(float);
    int*   cnt       = (int*)ws;   ws += N_GRAPHS * sizeof(int);

    const int nodeB = (N_NODES + 255) / 256;
    const int edgeB = (N_EDGES + 255) / 256;
    const int waveB = (N_NODES * 64 + 255) / 256;  // one wave per node

    // CSR + norm precompute (shared by all 4 layers)
    init_k<<<nodeB, 256, 0, stream>>>(counts, total, gmax, gsum, cnt);
    hist_k<<<edgeB, 256, 0, stream>>>(dst, counts, slot_in);
    alloc_k<<<nodeB, 256, 0, stream>>>(counts, row_start, total);
    scatter_k<<<edgeB, 256, 0, stream>>>(src, dst, edge_attr, slot_in, row_start, csr);
    deg_dinv_k<<<waveB, 256, 0, stream>>>(csr, row_start, counts, dinv);
    normfix_k<<<waveB, 256, 0, stream>>>(csr, row_start, counts, dinv);

    const float* Wl[4] = {W0, W1, W2, W3};
    const float* bl[4] = {b0, b1, b2, b3};
    for (int l = 0; l < 4; ++l) {
        if (l == 0) gemm_k<IN_CH><<<3125, 256, 0, stream>>>(x, Wl[0], bufL);
        else        gemm_k<EMB>  <<<3125, 256, 0, stream>>>(bufH, Wl[l], bufL);
        fused_agg_k<<<waveB, 256, 0, stream>>>(bufL, csr, row_start, counts, dinv, bl[l], bufH);
    }

    pool_k<<<(((N_NODES + POOL_CHUNK - 1) / POOL_CHUNK) * 64 + 255) / 256, 256, 0, stream>>>(
        bufH, batch, gmax, gsum, cnt);
    final_k<<<1, 64, 0, stream>>>(gmax, gsum, cnt, Wout, bout, out);
}

// Round 6
// 433.146 us; speedup vs baseline: 2.7067x; 1.1907x over previous
//
#include <hip/hip_runtime.h>
#include <math.h>
#include <limits.h>

#define N_NODES 50000
#define N_EDGES 800000
#define N_GRAPHS 64
#define IN_CH 128
#define EMB 64
#define POOL_CHUNK 16   // 50000 = 16 * 3125 exactly; 3125 waves -> ~12 waves/CU

// ---------- init: counts=0, total=0, pool accumulators ----------
__global__ void init_k(int* counts, int* total, int* gmax, float* gsum, int* cnt) {
    int i = blockIdx.x * blockDim.x + threadIdx.x;
    if (i < N_NODES) counts[i] = 0;
    if (i == 0) *total = 0;
    if (i < N_GRAPHS * EMB) { gmax[i] = INT_MIN; gsum[i] = 0.f; }
    if (i < N_GRAPHS) cnt[i] = 0;
}

// ---------- histogram: in-degree count; returned old value = stable slot ----------
__global__ void hist_k(const int* __restrict__ dst, int* counts,
                       int* __restrict__ slot_in) {
    int e = blockIdx.x * blockDim.x + threadIdx.x;
    if (e >= N_EDGES) return;
    slot_in[e] = atomicAdd(&counts[dst[e]], 1);
}

// ---------- CSR range allocation: wave-scan + one atomic per wave ----------
__global__ void alloc_k(const int* __restrict__ counts, int* __restrict__ row_start,
                        int* total) {
    int i = blockIdx.x * blockDim.x + threadIdx.x;
    int lane = threadIdx.x & 63;
    int c = (i < N_NODES) ? counts[i] : 0;
    int inc = c;
    for (int off = 1; off < 64; off <<= 1) {
        int v = __shfl_up(inc, off);
        if (lane >= off) inc += v;
    }
    int base;
    if (lane == 63) base = atomicAdd(total, inc);
    base = __shfl(base, 63);
    if (i < N_NODES) row_start[i] = base + inc - c;
}

// ---------- scatter edges into CSR slots (atomic-free); store (src, raw w) ----------
__global__ void scatter_k(const int* __restrict__ src, const int* __restrict__ dst,
                          const float* __restrict__ w, const int* __restrict__ slot_in,
                          const int* __restrict__ row_start, int2* __restrict__ csr) {
    int e = blockIdx.x * blockDim.x + threadIdx.x;
    if (e >= N_EDGES) return;
    int d = dst[e];
    int slot = row_start[d] + slot_in[e];
    csr[slot] = make_int2(src[e], __float_as_int(w[e]));
}

// ---------- per-node weighted degree (wave reduction over CSR range) -> dinv ----------
__global__ __launch_bounds__(256) void deg_dinv_k(const int2* __restrict__ csr,
                                                  const int* __restrict__ row_start,
                                                  const int* __restrict__ counts,
                                                  float* __restrict__ dinv) {
    int node = (blockIdx.x * blockDim.x + threadIdx.x) >> 6;
    int lane = threadIdx.x & 63;
    if (node >= N_NODES) return;
    int beg = row_start[node], n = counts[node];
    float s = 0.f;
    for (int i = lane; i < n; i += 64) s += __int_as_float(csr[beg + i].y);
    for (int off = 32; off > 0; off >>= 1) s += __shfl_down(s, off);
    if (lane == 0) {
        float d = 1.0f + s;  // self-loop weight 1
        dinv[node] = d > 0.f ? rsqrtf(d) : 0.f;
    }
}

// ---------- rewrite csr.y: raw w -> norm = dinv[s] * w * dinv[d] ----------
__global__ __launch_bounds__(256) void normfix_k(int2* __restrict__ csr,
                                                 const int* __restrict__ row_start,
                                                 const int* __restrict__ counts,
                                                 const float* __restrict__ dinv) {
    int node = (blockIdx.x * blockDim.x + threadIdx.x) >> 6;
    int lane = threadIdx.x & 63;
    if (node >= N_NODES) return;
    int beg = row_start[node], n = counts[node];
    float dd = dinv[node];
    for (int i = lane; i < n; i += 64) {
        int2 r = csr[beg + i];
        float nm = dinv[r.x] * __int_as_float(r.y) * dd;
        csr[beg + i] = make_int2(r.x, __float_as_int(nm));
    }
}

// ---------- h = A @ W : LDS-tiled, 64x64 output tile, 4x4 register tile ----------
// A-tile in LDS with 16B-chunk XOR swizzle (kc ^ (r&3)) so the 4 row-groups a
// wave reads land in distinct banks (no room to pad: 32KB A + 32KB W = 64KB cap).
template<int K>
__global__ __launch_bounds__(256) void gemm_k(const float* __restrict__ A,
                                              const float* __restrict__ W,
                                              float* __restrict__ out) {
    __shared__ float Al[64 * K];
    __shared__ float Wl[K * EMB];
    int tid = threadIdx.x;
    long rowBase = (long)blockIdx.x * 64;
    int validRows = (int)min((long)64, (long)N_NODES - rowBase);

    // stage A tile (contiguous 64*K block in global), swizzled into LDS
    const float4* Ag = (const float4*)(A + rowBase * K);
    for (int i = tid; i < validRows * (K / 4); i += 256) {
        int r = i / (K / 4), kc = i % (K / 4);
        float4 v = Ag[(long)r * (K / 4) + kc];
        *(float4*)&Al[r * K + 4 * (kc ^ (r & 3))] = v;
    }
    // stage W (row-major K x 64)
    const float4* Wg = (const float4*)W;
    float4* Wl4 = (float4*)Wl;
    for (int i = tid; i < K * EMB / 4; i += 256) Wl4[i] = Wg[i];
    __syncthreads();

    int tc = tid & 15, tr = tid >> 4;      // 16 cols-groups x 16 row-groups
    int r0 = tr * 4, c0 = tc * 4;
    float acc[4][4] = {};
#pragma unroll 2
    for (int k = 0; k < K; k += 4) {
        int kc = k >> 2;
        float4 a[4], w[4];
#pragma unroll
        for (int i = 0; i < 4; ++i)
            a[i] = *(const float4*)&Al[(r0 + i) * K + 4 * (kc ^ i)];
#pragma unroll
        for (int j = 0; j < 4; ++j)
            w[j] = *(const float4*)&Wl[(k + j) * EMB + c0];
#pragma unroll
        for (int i = 0; i < 4; ++i) {
            const float* ai = (const float*)&a[i];
#pragma unroll
            for (int kk = 0; kk < 4; ++kk) {
                float av = ai[kk];
                const float* wk = (const float*)&w[kk];
#pragma unroll
                for (int j = 0; j < 4; ++j) acc[i][j] += av * wk[j];
            }
        }
    }
#pragma unroll
    for (int i = 0; i < 4; ++i) {
        long row = rowBase + r0 + i;
        if (row < N_NODES)
            *(float4*)&out[row * EMB + c0] =
                make_float4(acc[i][0], acc[i][1], acc[i][2], acc[i][3]);
    }
}

// ---------- fused aggregation: self-loop + bias + CSR gather + tanh ----------
__global__ __launch_bounds__(256) void fused_agg_k(const float* __restrict__ h,
                                                   const int2* __restrict__ csr,
                                                   const int* __restrict__ row_start,
                                                   const int* __restrict__ counts,
                                                   const float* __restrict__ dinv,
                                                   const float* __restrict__ b,
                                                   float* __restrict__ out) {
    int node = (blockIdx.x * blockDim.x + threadIdx.x) >> 6;
    int lane = threadIdx.x & 63;
    if (node >= N_NODES) return;
    float di = dinv[node];
    float acc = di * di * h[(long)node * EMB + lane] + b[lane];
    int e = row_start[node];
    int end = e + counts[node];
    for (; e + 3 < end; e += 4) {
        int2 r0 = csr[e], r1 = csr[e + 1], r2 = csr[e + 2], r3 = csr[e + 3];
        float v0 = h[(long)r0.x * EMB + lane];
        float v1 = h[(long)r1.x * EMB + lane];
        float v2 = h[(long)r2.x * EMB + lane];
        float v3 = h[(long)r3.x * EMB + lane];
        acc += __int_as_float(r0.y) * v0;
        acc += __int_as_float(r1.y) * v1;
        acc += __int_as_float(r2.y) * v2;
        acc += __int_as_float(r3.y) * v3;
    }
    for (; e < end; ++e) {
        int2 r0 = csr[e];
        acc += __int_as_float(r0.y) * h[(long)r0.x * EMB + lane];
    }
    out[(long)node * EMB + lane] = tanhf(acc);
}

// ---------- pooling ----------
__device__ inline int f2ord(float x) {
    int bb = __float_as_int(x);
    return bb >= 0 ? bb : (bb ^ 0x7fffffff);
}
__device__ inline float ord2f(int k) {
    return __int_as_float(k >= 0 ? k : (k ^ 0x7fffffff));
}

// wave = 16 contiguous nodes (batch sorted); lane = channel.
__global__ __launch_bounds__(256) void pool_k(const float* __restrict__ h,
                                              const int* __restrict__ batch,
                                              int* gmax, float* gsum, int* cnt) {
    int wave = (blockIdx.x * blockDim.x + threadIdx.x) >> 6;
    int lane = threadIdx.x & 63;
    int start = wave * POOL_CHUNK;
    if (start >= N_NODES) return;   // 50000 % 16 == 0 -> full chunks always
    int bsel = (lane < POOL_CHUNK) ? batch[start + lane] : 0;
    float v[POOL_CHUNK];
#pragma unroll
    for (int i = 0; i < POOL_CHUNK; ++i)
        v[i] = h[(long)(start + i) * EMB + lane];
    int curg = __shfl(bsel, 0);
    float mx = -INFINITY, sm = 0.f;
    int ct = 0;
#pragma unroll
    for (int i = 0; i < POOL_CHUNK; ++i) {
        int g = __shfl(bsel, i);
        if (g != curg) {
            atomicMax(&gmax[curg * EMB + lane], f2ord(mx));
            atomicAdd(&gsum[curg * EMB + lane], sm);
            if (lane == 0) atomicAdd(&cnt[curg], ct);
            curg = g; mx = -INFINITY; sm = 0.f; ct = 0;
        }
        mx = fmaxf(mx, v[i]);
        sm += v[i];
        ++ct;
    }
    atomicMax(&gmax[curg * EMB + lane], f2ord(mx));
    atomicAdd(&gsum[curg * EMB + lane], sm);
    if (lane == 0) atomicAdd(&cnt[curg], ct);
}

__global__ void final_k(const int* __restrict__ gmax, const float* __restrict__ gsum,
                        const int* __restrict__ cnt, const float* __restrict__ Wout,
                        const float* __restrict__ bout, float* __restrict__ out) {
    int g = threadIdx.x;
    if (g >= N_GRAPHS) return;
    float c = fmaxf((float)cnt[g], 1.0f);
    float acc = bout[0];
    for (int ch = 0; ch < EMB; ++ch) {
        acc += ord2f(gmax[g * EMB + ch]) * Wout[ch]
             + (gsum[g * EMB + ch] / c) * Wout[EMB + ch];
    }
    out[g] = acc;
}

extern "C" void kernel_launch(void* const* d_in, const int* in_sizes, int n_in,
                              void* d_out, int out_size, void* d_ws, size_t ws_size,
                              hipStream_t stream) {
    const float* x         = (const float*)d_in[0];
    const int*   edge_idx  = (const int*)d_in[1];
    const float* edge_attr = (const float*)d_in[2];
    const int*   batch     = (const int*)d_in[3];
    const float* W0 = (const float*)d_in[4];
    const float* b0 = (const float*)d_in[5];
    const float* W1 = (const float*)d_in[6];
    const float* b1 = (const float*)d_in[7];
    const float* W2 = (const float*)d_in[8];
    const float* b2 = (const float*)d_in[9];
    const float* W3 = (const float*)d_in[10];
    const float* b3 = (const float*)d_in[11];
    const float* Wout = (const float*)d_in[12];
    const float* bout = (const float*)d_in[13];
    float* out = (float*)d_out;

    const int* src = edge_idx;            // edge_index[0]
    const int* dst = edge_idx + N_EDGES;  // edge_index[1]

    // workspace layout (~36 MB)
    char* ws = (char*)d_ws;
    float* dinv      = (float*)ws; ws += (size_t)N_NODES * sizeof(float);
    int*   counts    = (int*)ws;   ws += (size_t)N_NODES * sizeof(int);
    int*   row_start = (int*)ws;   ws += (size_t)N_NODES * sizeof(int);
    int*   slot_in   = (int*)ws;   ws += (size_t)N_EDGES * sizeof(int);
    int*   total     = (int*)ws;   ws += 4 * sizeof(int);  // keep 16B alignment
    int2*  csr       = (int2*)ws;  ws += (size_t)N_EDGES * sizeof(int2);
    float* bufL      = (float*)ws; ws += (size_t)N_NODES * EMB * sizeof(float);
    float* bufH      = (float*)ws; ws += (size_t)N_NODES * EMB * sizeof(float);
    int*   gmax      = (int*)ws;   ws += N_GRAPHS * EMB * sizeof(int);
    float* gsum      = (float*)ws; ws += N_GRAPHS * EMB * sizeof(float);
    int*   cnt       = (int*)ws;   ws += N_GRAPHS * sizeof(int);

    const int nodeB = (N_NODES + 255) / 256;
    const int edgeB = (N_EDGES + 255) / 256;
    const int waveB = (N_NODES * 64 + 255) / 256;  // one wave per node
    const int gemmB = (N_NODES + 63) / 64;         // 782 blocks, 64-row tiles

    // CSR + norm precompute (shared by all 4 layers)
    init_k<<<nodeB, 256, 0, stream>>>(counts, total, gmax, gsum, cnt);
    hist_k<<<edgeB, 256, 0, stream>>>(dst, counts, slot_in);
    alloc_k<<<nodeB, 256, 0, stream>>>(counts, row_start, total);
    scatter_k<<<edgeB, 256, 0, stream>>>(src, dst, edge_attr, slot_in, row_start, csr);
    deg_dinv_k<<<waveB, 256, 0, stream>>>(csr, row_start, counts, dinv);
    normfix_k<<<waveB, 256, 0, stream>>>(csr, row_start, counts, dinv);

    const float* Wl[4] = {W0, W1, W2, W3};
    const float* bl[4] = {b0, b1, b2, b3};
    for (int l = 0; l < 4; ++l) {
        if (l == 0) gemm_k<IN_CH><<<gemmB, 256, 0, stream>>>(x, Wl[0], bufL);
        else        gemm_k<EMB>  <<<gemmB, 256, 0, stream>>>(bufH, Wl[l], bufL);
        fused_agg_k<<<waveB, 256, 0, stream>>>(bufL, csr, row_start, counts, dinv, bl[l], bufH);
    }

    pool_k<<<(((N_NODES + POOL_CHUNK - 1) / POOL_CHUNK) * 64 + 255) / 256, 256, 0, stream>>>(
        bufH, batch, gmax, gsum, cnt);
    final_k<<<1, 64, 0, stream>>>(gmax, gsum, cnt, Wout, bout, out);
}

// Round 7
// 424.270 us; speedup vs baseline: 2.7633x; 1.0209x over previous
//
#include <hip/hip_runtime.h>
#include <math.h>
#include <limits.h>

#define N_NODES 50000
#define N_EDGES 800000
#define N_GRAPHS 64
#define IN_CH 128
#define EMB 64
#define POOL_CHUNK 16   // 50000 = 16 * 3125 exactly; 3125 waves -> ~12 waves/CU
#define CPAD 32         // counts padded to one per 128B line (atomic contention /32)

// ---------- init: padded counts=0, total=0, pool accumulators ----------
__global__ void init_k(int* counts, int* total, int* gmax, float* gsum, int* cnt) {
    int i = blockIdx.x * blockDim.x + threadIdx.x;
    if (i < N_NODES * CPAD) counts[i] = 0;
    if (i == 0) *total = 0;
    if (i < N_GRAPHS * EMB) { gmax[i] = INT_MIN; gsum[i] = 0.f; }
    if (i < N_GRAPHS) cnt[i] = 0;
}

// ---------- histogram: in-degree count; returned old value = stable slot ----------
__global__ void hist_k(const int* __restrict__ dst, int* counts,
                       int* __restrict__ slot_in) {
    int e = blockIdx.x * blockDim.x + threadIdx.x;
    if (e >= N_EDGES) return;
    slot_in[e] = atomicAdd(&counts[(size_t)dst[e] * CPAD], 1);
}

// ---------- CSR range allocation: wave-scan + one atomic per wave ----------
// emits compact row_start/row_end so downstream reads stay coalesced
__global__ void alloc_k(const int* __restrict__ counts, int* __restrict__ row_start,
                        int* __restrict__ row_end, int* total) {
    int i = blockIdx.x * blockDim.x + threadIdx.x;
    int lane = threadIdx.x & 63;
    int c = (i < N_NODES) ? counts[(size_t)i * CPAD] : 0;
    int inc = c;
    for (int off = 1; off < 64; off <<= 1) {
        int v = __shfl_up(inc, off);
        if (lane >= off) inc += v;
    }
    int base;
    if (lane == 63) base = atomicAdd(total, inc);
    base = __shfl(base, 63);
    int excl = base + inc - c;
    if (i < N_NODES) { row_start[i] = excl; row_end[i] = excl + c; }
}

// ---------- scatter edges into CSR slots (atomic-free); store (src, raw w) ----------
__global__ void scatter_k(const int* __restrict__ src, const int* __restrict__ dst,
                          const float* __restrict__ w, const int* __restrict__ slot_in,
                          const int* __restrict__ row_start, int2* __restrict__ csr) {
    int e = blockIdx.x * blockDim.x + threadIdx.x;
    if (e >= N_EDGES) return;
    int d = dst[e];
    int slot = row_start[d] + slot_in[e];
    csr[slot] = make_int2(src[e], __float_as_int(w[e]));
}

// ---------- per-node weighted degree (wave reduction over CSR range) -> dinv ----------
__global__ __launch_bounds__(256) void deg_dinv_k(const int2* __restrict__ csr,
                                                  const int* __restrict__ row_start,
                                                  const int* __restrict__ row_end,
                                                  float* __restrict__ dinv) {
    int node = (blockIdx.x * blockDim.x + threadIdx.x) >> 6;
    int lane = threadIdx.x & 63;
    if (node >= N_NODES) return;
    int beg = row_start[node], end = row_end[node];
    float s = 0.f;
    for (int i = beg + lane; i < end; i += 64) s += __int_as_float(csr[i].y);
    for (int off = 32; off > 0; off >>= 1) s += __shfl_down(s, off);
    if (lane == 0) {
        float d = 1.0f + s;  // self-loop weight 1
        dinv[node] = d > 0.f ? rsqrtf(d) : 0.f;
    }
}

// ---------- rewrite csr.y: raw w -> norm = dinv[s] * w * dinv[d] ----------
__global__ __launch_bounds__(256) void normfix_k(int2* __restrict__ csr,
                                                 const int* __restrict__ row_start,
                                                 const int* __restrict__ row_end,
                                                 const float* __restrict__ dinv) {
    int node = (blockIdx.x * blockDim.x + threadIdx.x) >> 6;
    int lane = threadIdx.x & 63;
    if (node >= N_NODES) return;
    int beg = row_start[node], end = row_end[node];
    float dd = dinv[node];
    for (int i = beg + lane; i < end; i += 64) {
        int2 r = csr[i];
        float nm = dinv[r.x] * __int_as_float(r.y) * dd;
        csr[i] = make_int2(r.x, __float_as_int(nm));
    }
}

// ---------- h = A @ W : LDS-tiled, 64x64 output tile, 4x4 register tile ----------
template<int K>
__global__ __launch_bounds__(256) void gemm_k(const float* __restrict__ A,
                                              const float* __restrict__ W,
                                              float* __restrict__ out) {
    __shared__ float Al[64 * K];
    __shared__ float Wl[K * EMB];
    int tid = threadIdx.x;
    long rowBase = (long)blockIdx.x * 64;
    int validRows = (int)min((long)64, (long)N_NODES - rowBase);

    const float4* Ag = (const float4*)(A + rowBase * K);
    for (int i = tid; i < validRows * (K / 4); i += 256) {
        int r = i / (K / 4), kc = i % (K / 4);
        float4 v = Ag[(long)r * (K / 4) + kc];
        *(float4*)&Al[r * K + 4 * (kc ^ (r & 3))] = v;
    }
    const float4* Wg = (const float4*)W;
    float4* Wl4 = (float4*)Wl;
    for (int i = tid; i < K * EMB / 4; i += 256) Wl4[i] = Wg[i];
    __syncthreads();

    int tc = tid & 15, tr = tid >> 4;
    int r0 = tr * 4, c0 = tc * 4;
    float acc[4][4] = {};
#pragma unroll 2
    for (int k = 0; k < K; k += 4) {
        int kc = k >> 2;
        float4 a[4], w[4];
#pragma unroll
        for (int i = 0; i < 4; ++i)
            a[i] = *(const float4*)&Al[(r0 + i) * K + 4 * (kc ^ i)];
#pragma unroll
        for (int j = 0; j < 4; ++j)
            w[j] = *(const float4*)&Wl[(k + j) * EMB + c0];
#pragma unroll
        for (int i = 0; i < 4; ++i) {
            const float* ai = (const float*)&a[i];
#pragma unroll
            for (int kk = 0; kk < 4; ++kk) {
                float av = ai[kk];
                const float* wk = (const float*)&w[kk];
#pragma unroll
                for (int j = 0; j < 4; ++j) acc[i][j] += av * wk[j];
            }
        }
    }
#pragma unroll
    for (int i = 0; i < 4; ++i) {
        long row = rowBase + r0 + i;
        if (row < N_NODES)
            *(float4*)&out[row * EMB + c0] =
                make_float4(acc[i][0], acc[i][1], acc[i][2], acc[i][3]);
    }
}

// ---------- fused aggregation: self-loop + bias + CSR gather + tanh ----------
// one wave per node; lane = channel; 8 gathers in flight; nt store so the
// 12.8MB output stream doesn't evict the gather working set (h) in L2.
__global__ __launch_bounds__(256) void fused_agg_k(const float* __restrict__ h,
                                                   const int2* __restrict__ csr,
                                                   const int* __restrict__ row_start,
                                                   const int* __restrict__ row_end,
                                                   const float* __restrict__ dinv,
                                                   const float* __restrict__ b,
                                                   float* __restrict__ out) {
    int node = (blockIdx.x * blockDim.x + threadIdx.x) >> 6;
    int lane = threadIdx.x & 63;
    if (node >= N_NODES) return;
    float di = dinv[node];
    float acc = di * di * h[(long)node * EMB + lane] + b[lane];
    int e = row_start[node];
    int end = row_end[node];
    for (; e + 7 < end; e += 8) {
        int2 r[8];
        float v[8];
#pragma unroll
        for (int i = 0; i < 8; ++i) r[i] = csr[e + i];
#pragma unroll
        for (int i = 0; i < 8; ++i) v[i] = h[(long)r[i].x * EMB + lane];
#pragma unroll
        for (int i = 0; i < 8; ++i) acc += __int_as_float(r[i].y) * v[i];
    }
    for (; e + 3 < end; e += 4) {
        int2 r0 = csr[e], r1 = csr[e + 1], r2 = csr[e + 2], r3 = csr[e + 3];
        float v0 = h[(long)r0.x * EMB + lane];
        float v1 = h[(long)r1.x * EMB + lane];
        float v2 = h[(long)r2.x * EMB + lane];
        float v3 = h[(long)r3.x * EMB + lane];
        acc += __int_as_float(r0.y) * v0;
        acc += __int_as_float(r1.y) * v1;
        acc += __int_as_float(r2.y) * v2;
        acc += __int_as_float(r3.y) * v3;
    }
    for (; e < end; ++e) {
        int2 r0 = csr[e];
        acc += __int_as_float(r0.y) * h[(long)r0.x * EMB + lane];
    }
    __builtin_nontemporal_store(tanhf(acc), &out[(long)node * EMB + lane]);
}

// ---------- pooling ----------
__device__ inline int f2ord(float x) {
    int bb = __float_as_int(x);
    return bb >= 0 ? bb : (bb ^ 0x7fffffff);
}
__device__ inline float ord2f(int k) {
    return __int_as_float(k >= 0 ? k : (k ^ 0x7fffffff));
}

// wave = 16 contiguous nodes (batch sorted); lane = channel.
__global__ __launch_bounds__(256) void pool_k(const float* __restrict__ h,
                                              const int* __restrict__ batch,
                                              int* gmax, float* gsum, int* cnt) {
    int wave = (blockIdx.x * blockDim.x + threadIdx.x) >> 6;
    int lane = threadIdx.x & 63;
    int start = wave * POOL_CHUNK;
    if (start >= N_NODES) return;   // 50000 % 16 == 0 -> full chunks always
    int bsel = (lane < POOL_CHUNK) ? batch[start + lane] : 0;
    float v[POOL_CHUNK];
#pragma unroll
    for (int i = 0; i < POOL_CHUNK; ++i)
        v[i] = h[(long)(start + i) * EMB + lane];
    int curg = __shfl(bsel, 0);
    float mx = -INFINITY, sm = 0.f;
    int ct = 0;
#pragma unroll
    for (int i = 0; i < POOL_CHUNK; ++i) {
        int g = __shfl(bsel, i);
        if (g != curg) {
            atomicMax(&gmax[curg * EMB + lane], f2ord(mx));
            atomicAdd(&gsum[curg * EMB + lane], sm);
            if (lane == 0) atomicAdd(&cnt[curg], ct);
            curg = g; mx = -INFINITY; sm = 0.f; ct = 0;
        }
        mx = fmaxf(mx, v[i]);
        sm += v[i];
        ++ct;
    }
    atomicMax(&gmax[curg * EMB + lane], f2ord(mx));
    atomicAdd(&gsum[curg * EMB + lane], sm);
    if (lane == 0) atomicAdd(&cnt[curg], ct);
}

__global__ void final_k(const int* __restrict__ gmax, const float* __restrict__ gsum,
                        const int* __restrict__ cnt, const float* __restrict__ Wout,
                        const float* __restrict__ bout, float* __restrict__ out) {
    int g = threadIdx.x;
    if (g >= N_GRAPHS) return;
    float c = fmaxf((float)cnt[g], 1.0f);
    float acc = bout[0];
    for (int ch = 0; ch < EMB; ++ch) {
        acc += ord2f(gmax[g * EMB + ch]) * Wout[ch]
             + (gsum[g * EMB + ch] / c) * Wout[EMB + ch];
    }
    out[g] = acc;
}

extern "C" void kernel_launch(void* const* d_in, const int* in_sizes, int n_in,
                              void* d_out, int out_size, void* d_ws, size_t ws_size,
                              hipStream_t stream) {
    const float* x         = (const float*)d_in[0];
    const int*   edge_idx  = (const int*)d_in[1];
    const float* edge_attr = (const float*)d_in[2];
    const int*   batch     = (const int*)d_in[3];
    const float* W0 = (const float*)d_in[4];
    const float* b0 = (const float*)d_in[5];
    const float* W1 = (const float*)d_in[6];
    const float* b1 = (const float*)d_in[7];
    const float* W2 = (const float*)d_in[8];
    const float* b2 = (const float*)d_in[9];
    const float* W3 = (const float*)d_in[10];
    const float* b3 = (const float*)d_in[11];
    const float* Wout = (const float*)d_in[12];
    const float* bout = (const float*)d_in[13];
    float* out = (float*)d_out;

    const int* src = edge_idx;            // edge_index[0]
    const int* dst = edge_idx + N_EDGES;  // edge_index[1]

    // workspace layout (~43 MB)
    char* ws = (char*)d_ws;
    float* dinv      = (float*)ws; ws += (size_t)N_NODES * sizeof(float);
    int*   counts    = (int*)ws;   ws += (size_t)N_NODES * CPAD * sizeof(int);
    int*   row_start = (int*)ws;   ws += (size_t)N_NODES * sizeof(int);
    int*   row_end   = (int*)ws;   ws += (size_t)N_NODES * sizeof(int);
    int*   slot_in   = (int*)ws;   ws += (size_t)N_EDGES * sizeof(int);
    int*   total     = (int*)ws;   ws += 4 * sizeof(int);  // keep 16B alignment
    int2*  csr       = (int2*)ws;  ws += (size_t)N_EDGES * sizeof(int2);
    float* bufL      = (float*)ws; ws += (size_t)N_NODES * EMB * sizeof(float);
    float* bufH      = (float*)ws; ws += (size_t)N_NODES * EMB * sizeof(float);
    int*   gmax      = (int*)ws;   ws += N_GRAPHS * EMB * sizeof(int);
    float* gsum      = (float*)ws; ws += N_GRAPHS * EMB * sizeof(float);
    int*   cnt       = (int*)ws;   ws += N_GRAPHS * sizeof(int);

    const int nodeB = (N_NODES + 255) / 256;
    const int edgeB = (N_EDGES + 255) / 256;
    const int waveB = (N_NODES * 64 + 255) / 256;  // one wave per node
    const int gemmB = (N_NODES + 63) / 64;         // 782 blocks, 64-row tiles
    const int initB = (N_NODES * CPAD + 255) / 256;

    // CSR + norm precompute (shared by all 4 layers)
    init_k<<<initB, 256, 0, stream>>>(counts, total, gmax, gsum, cnt);
    hist_k<<<edgeB, 256, 0, stream>>>(dst, counts, slot_in);
    alloc_k<<<nodeB, 256, 0, stream>>>(counts, row_start, row_end, total);
    scatter_k<<<edgeB, 256, 0, stream>>>(src, dst, edge_attr, slot_in, row_start, csr);
    deg_dinv_k<<<waveB, 256, 0, stream>>>(csr, row_start, row_end, dinv);
    normfix_k<<<waveB, 256, 0, stream>>>(csr, row_start, row_end, dinv);

    const float* Wl[4] = {W0, W1, W2, W3};
    const float* bl[4] = {b0, b1, b2, b3};
    for (int l = 0; l < 4; ++l) {
        if (l == 0) gemm_k<IN_CH><<<gemmB, 256, 0, stream>>>(x, Wl[0], bufL);
        else        gemm_k<EMB>  <<<gemmB, 256, 0, stream>>>(bufH, Wl[l], bufL);
        fused_agg_k<<<waveB, 256, 0, stream>>>(bufL, csr, row_start, row_end, dinv, bl[l], bufH);
    }

    pool_k<<<(((N_NODES + POOL_CHUNK - 1) / POOL_CHUNK) * 64 + 255) / 256, 256, 0, stream>>>(
        bufH, batch, gmax, gsum, cnt);
    final_k<<<1, 64, 0, stream>>>(gmax, gsum, cnt, Wout, bout, out);
}